// Round 13
// baseline (1796.802 us; speedup 1.0000x reference)
//
#include <hip/hip_runtime.h>
#include <hip/hip_bf16.h>
#include <hip/hip_cooperative_groups.h>

namespace cg = cooperative_groups;

#define NN    100000
#define NE    1600000
#define INCH  512
#define HIDCH 256
#define OUTCH 32
#define KHOPS 10
#define NEPAD (NE + 3 * NN)
#define NBKT  8
#define BDIV  12500            // NN / NBKT
#define BCAP  204800           // per-bucket capacity (mean 200K + 11 sigma)
#define EPB_A 8192             // edges per block, bucket phase
#define EPB_B 2048             // edges per block, fill phase

typedef __attribute__((ext_vector_type(8))) short short8;
typedef __attribute__((ext_vector_type(4))) float f32x4;

#define GLOAD_LDS16(gsrc, ldst) \
  __builtin_amdgcn_global_load_lds((const __attribute__((address_space(1))) void*)(gsrc), \
                                   (__attribute__((address_space(3))) void*)(ldst), 16, 0, 0)

// ---------------- workspace layout ----------------
constexpr size_t ws_align(size_t x) { return (x + 255) & ~(size_t)255; }
constexpr size_t USZ = ws_align((size_t)(NN + 1) * 32 * 2);   // one U table (+pad row)
constexpr size_t USH = USZ / 2;                                // stride in ushorts
constexpr size_t OFF_U0    = 0;                                          // 11 tables u0..u10
constexpr size_t OFF_W1TH  = OFF_U0    + 11 * USZ;                       // [256][512] bf16
constexpr size_t OFF_W1TL  = OFF_W1TH  + ws_align((size_t)HIDCH*INCH*2);
constexpr size_t OFF_W2TH  = OFF_W1TL  + ws_align((size_t)HIDCH*INCH*2); // [32][256] bf16
constexpr size_t OFF_W2TL  = OFF_W2TH  + ws_align((size_t)OUTCH*HIDCH*2);
constexpr size_t OFF_DEG   = OFF_W2TL  + ws_align((size_t)OUTCH*HIDCH*2); // [NN] int
constexpr size_t OFF_DIS   = OFF_DEG   + ws_align((size_t)NN*4);          // [NN] f32
constexpr size_t OFF_RP    = OFF_DIS   + ws_align((size_t)NN*4);          // [NN+1] int (positions)
constexpr size_t OFF_CUR   = OFF_RP    + ws_align((size_t)(NN+1)*4);      // [NN] int (by node)
constexpr size_t OFF_NAP   = OFF_CUR   + ws_align((size_t)NN*4);          // [NN] int node-at-pos
constexpr size_t OFF_POSV  = OFF_NAP   + ws_align((size_t)NN*4);          // [NN] int pos-of-node
constexpr size_t OFF_PDGP  = OFF_POSV  + ws_align((size_t)NN*4);          // [NN] int padded deg at pos
constexpr size_t OFF_D2P   = OFF_PDGP  + ws_align((size_t)NN*4);          // [NN] f32 dis^2 at pos
constexpr size_t OFF_DSQP  = OFF_D2P   + ws_align((size_t)NN*4);          // [NN] f32 sqrt(deg) at pos
constexpr size_t OFF_CSR   = OFF_DSQP  + ws_align((size_t)NN*4);          // [NEPAD] int (pos-translated src)
constexpr size_t OFF_PART  = OFF_CSR   + ws_align((size_t)NEPAD*4);       // [128] int
constexpr size_t OFF_OFFS  = OFF_PART  + ws_align(512);                   // [128] int
constexpr size_t OFF_BCNT  = OFF_OFFS  + ws_align(512);                   // [8] int
constexpr size_t OFF_BINH  = OFF_BCNT  + ws_align(32);                    // [64] int
constexpr size_t OFF_BINO  = OFF_BINH  + ws_align(256);                   // [64] int
constexpr size_t OFF_BINC  = OFF_BINO  + ws_align(256);                   // [64] int
constexpr size_t OFF_EPK8  = OFF_BINC  + ws_align(256);                   // [8][BCAP] int2

// ---------------- bf16 helpers ----------------
__device__ __forceinline__ unsigned short bf16_rne(float f) {
  unsigned int u = __float_as_uint(f);
  u += 0x7fffu + ((u >> 16) & 1u);
  return (unsigned short)(u >> 16);
}
__device__ __forceinline__ float bf16_to_f32(unsigned short h) {
  return __uint_as_float(((unsigned int)h) << 16);
}
__device__ __forceinline__ float bflo(unsigned int w) {
  return __uint_as_float(w << 16);
}
__device__ __forceinline__ float bfhi(unsigned int w) {
  return __uint_as_float(w & 0xffff0000u);
}

// ---------------- phase A: bucket edges by destination range + count deg ----------
__global__ __launch_bounds__(256) void k_bucket(const int* __restrict__ ei,
                                                int* __restrict__ deg,
                                                int* __restrict__ bcnt,
                                                int2* __restrict__ epk8) {
  __shared__ int hist[NBKT], rbase[NBKT], lcur[NBKT];
  const int t = threadIdx.x;
  const int e0 = blockIdx.x * EPB_A;
  if (t < NBKT) hist[t] = 0;
  __syncthreads();
  for (int i = t; i < EPB_A; i += 256) {
    int e = e0 + i;
    if (e < NE) {
      int c = ei[NE + e];
      atomicAdd(&deg[c], 1);
      atomicAdd(&hist[c / BDIV], 1);
    }
  }
  __syncthreads();
  if (t < NBKT) {
    rbase[t] = atomicAdd(&bcnt[t], hist[t]);
    lcur[t] = 0;
  }
  __syncthreads();
  for (int i = t; i < EPB_A; i += 256) {
    int e = e0 + i;
    if (e < NE) {
      int r = ei[e], c = ei[NE + e];
      int b = c / BDIV;
      int slot = atomicAdd(&lcur[b], 1);
      epk8[(size_t)b * BCAP + rbase[b] + slot] = make_int2(r, c);
    }
  }
}

// dis + zero pad rows of u0..u9 + degree histogram (fused)
__global__ __launch_bounds__(256) void k_dis(const int* __restrict__ deg,
                                             float* __restrict__ dis,
                                             unsigned short* __restrict__ u0,
                                             int* __restrict__ binh) {
  __shared__ int h[64];
  const int t = threadIdx.x;
  if (t < 64) h[t] = 0;
  __syncthreads();
  int v = blockIdx.x * 256 + t;
  if (v < NN) {
    int d = deg[v];
    dis[v] = d > 0 ? rsqrtf((float)d) : 0.0f;
    int bin = ((d + 3) & ~3) >> 2;
    if (bin > 63) bin = 63;
    atomicAdd(&h[bin], 1);
  }
  __syncthreads();
  if (t < 64 && h[t]) atomicAdd(&binh[t], h[t]);
  if (blockIdx.x == 0 && t < 160) {
    int tab = t >> 4, li = t & 15;
    ((unsigned int*)(u0 + (size_t)tab * USH))[(size_t)NN * 16 + li] = 0;
  }
}

__global__ __launch_bounds__(64) void k_binscan(const int* __restrict__ binh,
                                                int* __restrict__ bino,
                                                int* __restrict__ binc) {
  __shared__ int s[64];
  int t = threadIdx.x;
  int v = binh[t];
  s[t] = v;
  __syncthreads();
  for (int d = 1; d < 64; d <<= 1) {
    int x = (t >= d) ? s[t - d] : 0;
    __syncthreads();
    s[t] += x;
    __syncthreads();
  }
  bino[t] = s[t] - v;
  binc[t] = s[t] - v;
}

// place nodes into degree-sorted positions (two-level reservation)
__global__ __launch_bounds__(256) void k_place(const int* __restrict__ deg,
                                               int* __restrict__ binc,
                                               int* __restrict__ nap,
                                               int* __restrict__ posv,
                                               int* __restrict__ pdgp) {
  __shared__ int h[64], rb[64], lc[64];
  const int t = threadIdx.x;
  if (t < 64) h[t] = 0;
  __syncthreads();
  int v = blockIdx.x * 256 + t;
  int pdeg = 0, bin = 0;
  bool valid = v < NN;
  if (valid) {
    pdeg = (deg[v] + 3) & ~3;
    bin = pdeg >> 2;
    if (bin > 63) bin = 63;
    atomicAdd(&h[bin], 1);
  }
  __syncthreads();
  if (t < 64) {
    rb[t] = h[t] ? atomicAdd(&binc[t], h[t]) : 0;
    lc[t] = 0;
  }
  __syncthreads();
  if (valid) {
    int slot = atomicAdd(&lc[bin], 1);
    int pos = rb[bin] + slot;
    nap[pos] = v;
    posv[v] = pos;
    pdgp[pos] = pdeg;
  }
}

// ---------------- exclusive scan over pdgp ----------------
__global__ __launch_bounds__(256) void k_scan1(const int* __restrict__ pdgp,
                                               int* __restrict__ rp,
                                               int* __restrict__ part) {
  __shared__ int s[256];
  int b = blockIdx.x, t = threadIdx.x;
  int base = b * 1024 + t * 4;
  int v0 = (base + 0 < NN) ? pdgp[base + 0] : 0;
  int v1 = (base + 1 < NN) ? pdgp[base + 1] : 0;
  int v2 = (base + 2 < NN) ? pdgp[base + 2] : 0;
  int v3 = (base + 3 < NN) ? pdgp[base + 3] : 0;
  int tot = v0 + v1 + v2 + v3;
  s[t] = tot;
  __syncthreads();
  for (int d = 1; d < 256; d <<= 1) {
    int x = (t >= d) ? s[t - d] : 0;
    __syncthreads();
    s[t] += x;
    __syncthreads();
  }
  int excl = s[t] - tot;
  if (t == 255) part[b] = s[255];
  if (base + 0 < NN) rp[base + 0] = excl;
  if (base + 1 < NN) rp[base + 1] = excl + v0;
  if (base + 2 < NN) rp[base + 2] = excl + v0 + v1;
  if (base + 3 < NN) rp[base + 3] = excl + v0 + v1 + v2;
}

__global__ __launch_bounds__(128) void k_scan2(const int* __restrict__ part,
                                               int* __restrict__ offs) {
  __shared__ int s[128];
  int t = threadIdx.x;
  int v = (t < 98) ? part[t] : 0;
  s[t] = v;
  __syncthreads();
  for (int d = 1; d < 128; d <<= 1) {
    int x = (t >= d) ? s[t - d] : 0;
    __syncthreads();
    s[t] += x;
    __syncthreads();
  }
  if (t < 98) offs[t] = s[t] - v;
}

__global__ __launch_bounds__(256) void k_scan3(int* __restrict__ rp,
                                               const int* __restrict__ offs,
                                               const int* __restrict__ part) {
  int b = blockIdx.x, t = threadIdx.x;
  int o = offs[b];
  int base = b * 1024 + t * 4;
#pragma unroll
  for (int j = 0; j < 4; ++j) {
    int i = base + j;
    if (i < NN) rp[i] += o;
  }
  if (b == 0 && t == 0) rp[NN] = offs[97] + part[97];
}

// cur (by node) + per-position dis^2 / sqrt(deg)
__global__ __launch_bounds__(256) void k_curinit(const int* __restrict__ nap,
                                                 const int* __restrict__ rp,
                                                 const int* __restrict__ deg,
                                                 const float* __restrict__ dis,
                                                 int* __restrict__ cur,
                                                 float* __restrict__ d2p,
                                                 float* __restrict__ dsqp) {
  int p = blockIdx.x * 256 + threadIdx.x;
  if (p < NN) {
    int v = nap[p];
    cur[v] = rp[p];
    float dv = dis[v];
    d2p[p] = dv * dv;
    int d = deg[v];
    dsqp[p] = d > 0 ? sqrtf((float)d) : 0.0f;
  }
}

// ---------------- phase B: fill CSR (position-translated src), XCD-matched --------
__global__ __launch_bounds__(256) void k_fill2(const int2* __restrict__ epk8,
                                               const int* __restrict__ bcnt,
                                               const int* __restrict__ posv,
                                               int* __restrict__ cur,
                                               int* __restrict__ csrc) {
  const int bucket = blockIdx.x & 7;
  const int chunk = blockIdx.x >> 3;
  const int cnt = bcnt[bucket];
  const int lo = chunk * EPB_B;
  int n = cnt - lo;
  if (n > EPB_B) n = EPB_B;
  const int2* src = epk8 + (size_t)bucket * BCAP + lo;
  for (int i = threadIdx.x; i < n; i += 256) {
    int2 rc = src[i];
    int p = atomicAdd(&cur[rc.y], 1);
    csrc[p] = posv[rc.x];
  }
}

// pad each position's slots up to rounded length with dummy pos = NN (zero row)
__global__ __launch_bounds__(256) void k_pad(const int* __restrict__ nap,
                                             const int* __restrict__ cur,
                                             const int* __restrict__ rp,
                                             int* __restrict__ csrc) {
  int p = blockIdx.x * 256 + threadIdx.x;
  if (p < NN) {
    int v = nap[p];
    int q = cur[v], e = rp[p + 1];
    for (; q < e; ++q) csrc[q] = NN;
  }
}

// ---------------- split-transpose: dst[n][k] = split(src[k][n]) ----------------
__global__ __launch_bounds__(256) void k_splitT(const float* __restrict__ src,
                                                unsigned short* __restrict__ dh,
                                                unsigned short* __restrict__ dl,
                                                int K, int N) {
  int idx = blockIdx.x * 256 + threadIdx.x;
  if (idx >= K * N) return;
  int n = idx / K, k = idx - n * K;
  float v = src[(size_t)k * N + n];
  unsigned short h = bf16_rne(v);
  dh[idx] = h;
  dl[idx] = bf16_rne(v - bf16_to_f32(h));
}

// ---------------- fused MLP: u0[pos]=bf16(dis*h), out=g0*h (r12, unchanged) -------
__global__ __launch_bounds__(512, 2) void k_mlp(const float* __restrict__ X,
                                                const unsigned short* __restrict__ W1Th,
                                                const float* __restrict__ bias1,
                                                const unsigned short* __restrict__ W2Th,
                                                const float* __restrict__ bias2,
                                                const float* __restrict__ gamma,
                                                const float* __restrict__ dis,
                                                const int* __restrict__ posv,
                                                unsigned short* __restrict__ u0,
                                                float* __restrict__ out) {
  __shared__ __align__(16) unsigned short Ah[2][4096];   // 16 KB (reused: W2 stage)
  __shared__ __align__(16) unsigned short Bh[2][8192];   // 32 KB (reused: h1 halves)
  const int t = threadIdx.x;
  const int m0 = blockIdx.x * 128;
  const int w = t >> 6, lane = t & 63;
  const int wm = w >> 2, wn = w & 3;

  const int arow = t >> 2;
  const int achk = t & 3;
  int axrow = m0 + arow; if (axrow >= NN) axrow = NN - 1;
  const float* aptr = X + (size_t)axrow * INCH + achk * 8;
  int aidx = (arow >> 4) * 512 + ((arow & 15) + achk * 16) * 8;
  aidx ^= ((aidx >> 7) & 3) << 4;                      // XOR-swizzle (0 conflicts)
  const int aroff = (lane * 8) ^ (((lane >> 4) & 3) << 4);

  const int bn0 = (w * 16) + (lane & 15);
  const int bko = (lane >> 4) * 8;
  const unsigned short* bs0 = W1Th + (size_t)bn0 * INCH + bko;
  const unsigned short* bs1 = W1Th + (size_t)(bn0 + 128) * INCH + bko;

  f32x4 acc[4][4] = {};
  float4 av0, av1;

  av0 = *(const float4*)(aptr);
  av1 = *(const float4*)(aptr + 4);
  GLOAD_LDS16(bs0, &Bh[0][w * 512]);
  GLOAD_LDS16(bs1, &Bh[0][(w + 8) * 512]);
  {
    float af[8] = {av0.x, av0.y, av0.z, av0.w, av1.x, av1.y, av1.z, av1.w};
    short8 ah;
#pragma unroll
    for (int i = 0; i < 8; ++i) {
      unsigned int u = __float_as_uint(af[i]);
      ah[i] = (short)((u + 0x7fffu + ((u >> 16) & 1u)) >> 16);
    }
    *(short8*)&Ah[0][aidx] = ah;
  }
  __syncthreads();

#pragma unroll
  for (int it = 0; it < 16; ++it) {
    const int cur = it & 1, nxt = cur ^ 1;
    const int k0 = it * 32;
    if (it < 15) {
      av0 = *(const float4*)(aptr + k0 + 32);
      av1 = *(const float4*)(aptr + k0 + 36);
      GLOAD_LDS16(bs0 + k0 + 32, &Bh[nxt][w * 512]);
      GLOAD_LDS16(bs1 + k0 + 32, &Bh[nxt][(w + 8) * 512]);
    }
    short8 afrag[4];
#pragma unroll
    for (int mf = 0; mf < 4; ++mf)
      afrag[mf] = *(const short8*)&Ah[cur][(wm * 4 + mf) * 512 + aroff];
#pragma unroll
    for (int nf = 0; nf < 4; ++nf) {
      short8 bfh = *(const short8*)&Bh[cur][(wn * 4 + nf) * 512 + lane * 8];
#pragma unroll
      for (int mf = 0; mf < 4; ++mf) {
        acc[mf][nf] = __builtin_amdgcn_mfma_f32_16x16x32_bf16(afrag[mf], bfh, acc[mf][nf], 0, 0, 0);
      }
    }
    if (it < 15) {
      float af[8] = {av0.x, av0.y, av0.z, av0.w, av1.x, av1.y, av1.z, av1.w};
      short8 ah;
#pragma unroll
      for (int i = 0; i < 8; ++i) {
        unsigned int u = __float_as_uint(af[i]);
        ah[i] = (short)((u + 0x7fffu + ((u >> 16) & 1u)) >> 16);
      }
      *(short8*)&Ah[nxt][aidx] = ah;
    }
    __syncthreads();
  }

  // ================= fused GEMM2 =================
  unsigned short* AhF = &Ah[0][0];   // W2Th staged here (16 units)
  unsigned short* BhF = &Bh[0][0];   // h1 half (32 units of 512)

  {
#pragma unroll
    for (int q = 0; q < 2; ++q) {
      int u = w * 2 + q;
      int ngrp = u >> 3, k32 = u & 7;
      const unsigned short* src = W2Th + (size_t)(ngrp * 16 + (lane & 15)) * HIDCH
                                       + k32 * 32 + (lane >> 4) * 8;
      GLOAD_LDS16(src, &AhF[u * 512]);
    }
  }

  const int row15b = (lane >> 4) << 2;
  const int kcol = lane & 15;
  float bset[4];
#pragma unroll
  for (int nf = 0; nf < 4; ++nf) bset[nf] = bias1[wn * 64 + nf * 16 + kcol];

  if (wn < 2) {
    const int kbase = wn * 64;
#pragma unroll
    for (int nf = 0; nf < 4; ++nf) {
      int kh = kbase + nf * 16 + kcol;
      int base = ((wm * 4) * 4 + (kh >> 5)) * 512 + ((kh >> 3) & 3) * 128 + (kh & 7);
#pragma unroll
      for (int mf = 0; mf < 4; ++mf) {
#pragma unroll
        for (int r = 0; r < 4; ++r) {
          float h = fmaxf(acc[mf][nf][r] + bset[nf], 0.f);
          BhF[base + mf * 2048 + (row15b + r) * 8] = bf16_rne(h);
        }
      }
    }
  }
  __syncthreads();

  f32x4 acc2[2] = {};
#pragma unroll
  for (int s = 0; s < 4; ++s) {
    short8 a2 = *(const short8*)&BhF[(w * 4 + s) * 512 + lane * 8];
#pragma unroll
    for (int nf = 0; nf < 2; ++nf) {
      short8 bf = *(const short8*)&AhF[(nf * 8 + s) * 512 + lane * 8];
      acc2[nf] = __builtin_amdgcn_mfma_f32_16x16x32_bf16(a2, bf, acc2[nf], 0, 0, 0);
    }
  }
  __syncthreads();

  if (wn >= 2) {
    const int kbase = (wn - 2) * 64;
#pragma unroll
    for (int nf = 0; nf < 4; ++nf) {
      int kh = kbase + nf * 16 + kcol;
      int base = ((wm * 4) * 4 + (kh >> 5)) * 512 + ((kh >> 3) & 3) * 128 + (kh & 7);
#pragma unroll
      for (int mf = 0; mf < 4; ++mf) {
#pragma unroll
        for (int r = 0; r < 4; ++r) {
          float h = fmaxf(acc[mf][nf][r] + bset[nf], 0.f);
          BhF[base + mf * 2048 + (row15b + r) * 8] = bf16_rne(h);
        }
      }
    }
  }
  __syncthreads();

#pragma unroll
  for (int s = 0; s < 4; ++s) {
    short8 a2 = *(const short8*)&BhF[(w * 4 + s) * 512 + lane * 8];
#pragma unroll
    for (int nf = 0; nf < 2; ++nf) {
      short8 bf = *(const short8*)&AhF[(nf * 8 + 4 + s) * 512 + lane * 8];
      acc2[nf] = __builtin_amdgcn_mfma_f32_16x16x32_bf16(a2, bf, acc2[nf], 0, 0, 0);
    }
  }

  const float g0 = gamma[0];
  const float b2c[2] = {bias2[kcol], bias2[16 + kcol]};
#pragma unroll
  for (int nf = 0; nf < 2; ++nf) {
#pragma unroll
    for (int r = 0; r < 4; ++r) {
      int row = m0 + w * 16 + row15b + r;
      if (row < NN) {
        float h = acc2[nf][r] + b2c[nf];
        float dv = dis[row];
        size_t op = (size_t)posv[row] * 32 + nf * 16 + kcol;
        u0[op] = bf16_rne(dv * h);
        out[(size_t)row * 32 + nf * 16 + kcol] = g0 * h;
      }
    }
  }
}

// ---------------- persistent propagation: 10 hops + merge, one dispatch -----------
// Cooperative launch; grid.sync() between hops. Same hop body/numerics as r11/r12.
__global__ __launch_bounds__(256) void k_prop(unsigned short* __restrict__ u0,
                                              const int* __restrict__ rp,
                                              const int* __restrict__ csrc,
                                              const float* __restrict__ d2p,
                                              const int* __restrict__ nap,
                                              const float* __restrict__ dsqp,
                                              const float* __restrict__ gamma,
                                              float* __restrict__ out) {
  cg::grid_group grid = cg::this_grid();
  const int t = threadIdx.x;
  const int g = t >> 4;                    // node slot 0..15
  const int li = t & 15;                   // lane in group (2 channels)
  const int nwb = NN / 16;                 // 6250 work-chunks per hop

  for (int k = 1; k <= KHOPS; ++k) {
    const unsigned int* Uin = (const unsigned int*)(u0 + (size_t)(k - 1) * USH);
    unsigned int* Uout = (unsigned int*)(u0 + (size_t)k * USH);
    for (int wb = blockIdx.x; wb < nwb; wb += gridDim.x) {
      const int p = wb * 16 + g;
      const int s = rp[p], e = rp[p + 1];  // multiples of 4 (pads -> pos NN zero row)
      float ax0 = 0.f, ay0 = 0.f, ax1 = 0.f, ay1 = 0.f;
      float ax2 = 0.f, ay2 = 0.f, ax3 = 0.f, ay3 = 0.f;
      int j = s;
      for (; j + 8 <= e; j += 8) {
        int4 sa = *(const int4*)&csrc[j];  // uniform within group -> broadcast
        int4 sb = *(const int4*)&csrc[j + 4];
        unsigned int w0 = Uin[(size_t)sa.x * 16 + li];
        unsigned int w1 = Uin[(size_t)sa.y * 16 + li];
        unsigned int w2 = Uin[(size_t)sa.z * 16 + li];
        unsigned int w3 = Uin[(size_t)sa.w * 16 + li];
        unsigned int w4 = Uin[(size_t)sb.x * 16 + li];
        unsigned int w5 = Uin[(size_t)sb.y * 16 + li];
        unsigned int w6 = Uin[(size_t)sb.z * 16 + li];
        unsigned int w7 = Uin[(size_t)sb.w * 16 + li];
        ax0 += bflo(w0); ay0 += bfhi(w0);
        ax1 += bflo(w1); ay1 += bfhi(w1);
        ax2 += bflo(w2); ay2 += bfhi(w2);
        ax3 += bflo(w3); ay3 += bfhi(w3);
        ax0 += bflo(w4); ay0 += bfhi(w4);
        ax1 += bflo(w5); ay1 += bfhi(w5);
        ax2 += bflo(w6); ay2 += bfhi(w6);
        ax3 += bflo(w7); ay3 += bfhi(w7);
      }
      if (j < e) {
        int4 sa = *(const int4*)&csrc[j];
        unsigned int w0 = Uin[(size_t)sa.x * 16 + li];
        unsigned int w1 = Uin[(size_t)sa.y * 16 + li];
        unsigned int w2 = Uin[(size_t)sa.z * 16 + li];
        unsigned int w3 = Uin[(size_t)sa.w * 16 + li];
        ax0 += bflo(w0); ay0 += bfhi(w0);
        ax1 += bflo(w1); ay1 += bfhi(w1);
        ax2 += bflo(w2); ay2 += bfhi(w2);
        ax3 += bflo(w3); ay3 += bfhi(w3);
      }
      const float Sx = (ax0 + ax1) + (ax2 + ax3);
      const float Sy = (ay0 + ay1) + (ay2 + ay3);
      const float d2 = d2p[p];
      unsigned int packed = (unsigned int)bf16_rne(d2 * Sx) |
                            ((unsigned int)bf16_rne(d2 * Sy) << 16);
      Uout[(size_t)p * 16 + li] = packed;
    }
    grid.sync();
  }

  // merge: out[v] += sum_k gamma_k * sqrt(deg) * u_k[pos]
  const unsigned short* u1 = u0 + USH;
  for (int idx = blockIdx.x * 256 + t; idx < NN * 16; idx += gridDim.x * 256) {
    const int p = idx >> 4;
    const int li2 = idx & 15;
    const int v = nap[p];
    const float f = dsqp[p];
    const size_t o = (size_t)v * 32 + li2 * 2;
    float2 acc = *(const float2*)&out[o];
#pragma unroll
    for (int k = 0; k < KHOPS; ++k) {
      unsigned int w = ((const unsigned int*)(u1 + (size_t)k * USH))[(size_t)p * 16 + li2];
      float gk = gamma[k + 1] * f;
      acc.x = fmaf(gk, bflo(w), acc.x);
      acc.y = fmaf(gk, bfhi(w), acc.y);
    }
    *(float2*)&out[o] = acc;
  }
}

extern "C" void kernel_launch(void* const* d_in, const int* in_sizes, int n_in,
                              void* d_out, int out_size, void* d_ws, size_t ws_size,
                              hipStream_t stream) {
  const float* x     = (const float*)d_in[0];
  const int*   ei    = (const int*)d_in[1];
  const float* W1    = (const float*)d_in[2];
  const float* b1    = (const float*)d_in[3];
  const float* W2    = (const float*)d_in[4];
  const float* b2    = (const float*)d_in[5];
  const float* gamma = (const float*)d_in[6];
  float* out = (float*)d_out;

  char* ws = (char*)d_ws;
  unsigned short* u0   = (unsigned short*)(ws + OFF_U0);
  unsigned short* w1th = (unsigned short*)(ws + OFF_W1TH);
  unsigned short* w1tl = (unsigned short*)(ws + OFF_W1TL);
  unsigned short* w2th = (unsigned short*)(ws + OFF_W2TH);
  unsigned short* w2tl = (unsigned short*)(ws + OFF_W2TL);
  int*   deg  = (int*)(ws + OFF_DEG);
  float* dis  = (float*)(ws + OFF_DIS);
  int*   rp   = (int*)(ws + OFF_RP);
  int*   cur  = (int*)(ws + OFF_CUR);
  int*   nap  = (int*)(ws + OFF_NAP);
  int*   posv = (int*)(ws + OFF_POSV);
  int*   pdgp = (int*)(ws + OFF_PDGP);
  float* d2p  = (float*)(ws + OFF_D2P);
  float* dsqp = (float*)(ws + OFF_DSQP);
  int*   csrc = (int*)(ws + OFF_CSR);
  int*   part = (int*)(ws + OFF_PART);
  int*   offs = (int*)(ws + OFF_OFFS);
  int*   bcnt = (int*)(ws + OFF_BCNT);
  int*   binh = (int*)(ws + OFF_BINH);
  int*   bino = (int*)(ws + OFF_BINO);
  int*   binc = (int*)(ws + OFF_BINC);
  int2*  epk8 = (int2*)(ws + OFF_EPK8);

  hipMemsetAsync(deg, 0, NN * sizeof(int), stream);
  hipMemsetAsync(bcnt, 0, NBKT * sizeof(int), stream);
  hipMemsetAsync(binh, 0, 64 * sizeof(int), stream);

  // weight prep (tiny)
  k_splitT<<<(INCH * HIDCH + 255) / 256, 256, 0, stream>>>(W1, w1th, w1tl, INCH, HIDCH);
  k_splitT<<<(HIDCH * OUTCH + 255) / 256, 256, 0, stream>>>(W2, w2th, w2tl, HIDCH, OUTCH);

  // graph prep: bucket (+deg), dis(+hist), degree-sort, scan, XCD-local fill, pad
  k_bucket<<<(NE + EPB_A - 1) / EPB_A, 256, 0, stream>>>(ei, deg, bcnt, epk8);
  k_dis<<<(NN + 255) / 256, 256, 0, stream>>>(deg, dis, u0, binh);
  k_binscan<<<1, 64, 0, stream>>>(binh, bino, binc);
  k_place<<<(NN + 255) / 256, 256, 0, stream>>>(deg, binc, nap, posv, pdgp);
  k_scan1<<<98, 256, 0, stream>>>(pdgp, rp, part);
  k_scan2<<<1, 128, 0, stream>>>(part, offs);
  k_scan3<<<98, 256, 0, stream>>>(rp, offs, part);
  k_curinit<<<(NN + 255) / 256, 256, 0, stream>>>(nap, rp, deg, dis, cur, d2p, dsqp);
  k_fill2<<<(BCAP / EPB_B) * NBKT, 256, 0, stream>>>(epk8, bcnt, posv, cur, csrc);
  k_pad<<<(NN + 255) / 256, 256, 0, stream>>>(nap, cur, rp, csrc);

  // fused MLP (gemm1 + gemm2): writes u0[pos] and out = g0*h
  k_mlp<<<(NN + 127) / 128, 512, 0, stream>>>(x, w1th, b1, w2th, b2, gamma, dis,
                                              posv, u0, out);

  // persistent cooperative propagation: 10 hops + merge in one dispatch
  int bpc = 0;
  hipOccupancyMaxActiveBlocksPerMultiprocessor(&bpc, (const void*)k_prop, 256, 0);
  if (bpc < 1) bpc = 1;
  if (bpc > 8) bpc = 8;
  int ngrid = bpc * 256;                   // MI355X: 256 CUs
  if (ngrid > NN / 16) ngrid = NN / 16;
  unsigned short* u0p = u0;
  void* args[] = {&u0p, &rp, &csrc, &d2p, &nap, &dsqp, (void*)&gamma, (void*)&out};
  hipLaunchCooperativeKernel((const void*)k_prop, dim3(ngrid), dim3(256),
                             args, 0, stream);
}

// Round 14
// 510.523 us; speedup vs baseline: 3.5195x; 3.5195x over previous
//
#include <hip/hip_runtime.h>
#include <hip/hip_bf16.h>

#define NN    100000
#define NE    1600000
#define INCH  512
#define HIDCH 256
#define OUTCH 32
#define KHOPS 10
#define NEPAD (NE + 3 * NN)
#define NBKT  8
#define BDIV  12500            // NN / NBKT
#define BCAP  204800           // per-bucket capacity (mean 200K + 11 sigma)
#define EPB_A 8192             // edges per block, bucket phase
#define EPB_B 2048             // edges per block, fill phase

typedef __attribute__((ext_vector_type(8))) short short8;
typedef __attribute__((ext_vector_type(4))) float f32x4;

#define GLOAD_LDS16(gsrc, ldst) \
  __builtin_amdgcn_global_load_lds((const __attribute__((address_space(1))) void*)(gsrc), \
                                   (__attribute__((address_space(3))) void*)(ldst), 16, 0, 0)

// ---------------- workspace layout ----------------
constexpr size_t ws_align(size_t x) { return (x + 255) & ~(size_t)255; }
constexpr size_t USZ = ws_align((size_t)(NN + 1) * 32 * 2);   // one U table (+pad row)
constexpr size_t USH = USZ / 2;                                // stride in ushorts
constexpr size_t OFF_U0    = 0;                                          // 11 tables u0..u10
constexpr size_t OFF_W1TH  = OFF_U0    + 11 * USZ;                       // [256][512] bf16
constexpr size_t OFF_W2TH  = OFF_W1TH  + ws_align((size_t)HIDCH*INCH*2); // [32][256] bf16
constexpr size_t OFF_DEG   = OFF_W2TH  + ws_align((size_t)OUTCH*HIDCH*2); // [NN] int
constexpr size_t OFF_DIS   = OFF_DEG   + ws_align((size_t)NN*4);          // [NN] f32
constexpr size_t OFF_RP    = OFF_DIS   + ws_align((size_t)NN*4);          // [NN+1] int (positions)
constexpr size_t OFF_CUR   = OFF_RP    + ws_align((size_t)(NN+1)*4);      // [NN] int (by node)
constexpr size_t OFF_NAP   = OFF_CUR   + ws_align((size_t)NN*4);          // [NN] int node-at-pos
constexpr size_t OFF_POSV  = OFF_NAP   + ws_align((size_t)NN*4);          // [NN] int pos-of-node
constexpr size_t OFF_PDGP  = OFF_POSV  + ws_align((size_t)NN*4);          // [NN] int padded deg at pos
constexpr size_t OFF_D2P   = OFF_PDGP  + ws_align((size_t)NN*4);          // [NN] f32 dis^2 at pos
constexpr size_t OFF_DSQP  = OFF_D2P   + ws_align((size_t)NN*4);          // [NN] f32 sqrt(deg) at pos
constexpr size_t OFF_CSR   = OFF_DSQP  + ws_align((size_t)NN*4);          // [NEPAD] int (pos-translated src)
constexpr size_t OFF_PART  = OFF_CSR   + ws_align((size_t)NEPAD*4);       // [128] int
constexpr size_t OFF_OFFS  = OFF_PART  + ws_align(512);                   // [128] int
constexpr size_t OFF_BCNT  = OFF_OFFS  + ws_align(512);                   // [8] int
constexpr size_t OFF_BINH  = OFF_BCNT  + ws_align(32);                    // [64] int
constexpr size_t OFF_BINC  = OFF_BINH  + ws_align(256);                   // [64] int
constexpr size_t OFF_EPK8  = OFF_BINC  + ws_align(256);                   // [8][BCAP] int2

// ---------------- bf16 helpers ----------------
__device__ __forceinline__ unsigned short bf16_rne(float f) {
  unsigned int u = __float_as_uint(f);
  u += 0x7fffu + ((u >> 16) & 1u);
  return (unsigned short)(u >> 16);
}
__device__ __forceinline__ float bf16_to_f32(unsigned short h) {
  return __uint_as_float(((unsigned int)h) << 16);
}
__device__ __forceinline__ float bflo(unsigned int w) {
  return __uint_as_float(w << 16);
}
__device__ __forceinline__ float bfhi(unsigned int w) {
  return __uint_as_float(w & 0xffff0000u);
}

// ---------------- zero init (deg, bcnt, binh) ----------------
__global__ __launch_bounds__(256) void k_zero(int* __restrict__ deg,
                                              int* __restrict__ bcnt,
                                              int* __restrict__ binh) {
  int i = blockIdx.x * 256 + threadIdx.x;
  if (i < NN) deg[i] = 0;
  if (blockIdx.x == 0) {
    if (threadIdx.x < NBKT) bcnt[threadIdx.x] = 0;
    if (threadIdx.x < 64) binh[threadIdx.x] = 0;
  }
}

// ---------------- phase A: bucket edges by destination range + count deg ----------
__global__ __launch_bounds__(256) void k_bucket(const int* __restrict__ ei,
                                                int* __restrict__ deg,
                                                int* __restrict__ bcnt,
                                                int2* __restrict__ epk8) {
  __shared__ int hist[NBKT], rbase[NBKT], lcur[NBKT];
  const int t = threadIdx.x;
  const int e0 = blockIdx.x * EPB_A;
  if (t < NBKT) hist[t] = 0;
  __syncthreads();
  for (int i = t; i < EPB_A; i += 256) {
    int e = e0 + i;
    if (e < NE) {
      int c = ei[NE + e];
      atomicAdd(&deg[c], 1);
      atomicAdd(&hist[c / BDIV], 1);
    }
  }
  __syncthreads();
  if (t < NBKT) {
    rbase[t] = atomicAdd(&bcnt[t], hist[t]);
    lcur[t] = 0;
  }
  __syncthreads();
  for (int i = t; i < EPB_A; i += 256) {
    int e = e0 + i;
    if (e < NE) {
      int r = ei[e], c = ei[NE + e];
      int b = c / BDIV;
      int slot = atomicAdd(&lcur[b], 1);
      epk8[(size_t)b * BCAP + rbase[b] + slot] = make_int2(r, c);
    }
  }
}

// dis + zero pad rows of u0..u9 + degree histogram (fused)
__global__ __launch_bounds__(256) void k_dis(const int* __restrict__ deg,
                                             float* __restrict__ dis,
                                             unsigned short* __restrict__ u0,
                                             int* __restrict__ binh) {
  __shared__ int h[64];
  const int t = threadIdx.x;
  if (t < 64) h[t] = 0;
  __syncthreads();
  int v = blockIdx.x * 256 + t;
  if (v < NN) {
    int d = deg[v];
    dis[v] = d > 0 ? rsqrtf((float)d) : 0.0f;
    int bin = ((d + 3) & ~3) >> 2;
    if (bin > 63) bin = 63;
    atomicAdd(&h[bin], 1);
  }
  __syncthreads();
  if (t < 64 && h[t]) atomicAdd(&binh[t], h[t]);
  if (blockIdx.x == 0 && t < 160) {
    int tab = t >> 4, li = t & 15;
    ((unsigned int*)(u0 + (size_t)tab * USH))[(size_t)NN * 16 + li] = 0;
  }
}

__global__ __launch_bounds__(64) void k_binscan(const int* __restrict__ binh,
                                                int* __restrict__ binc) {
  __shared__ int s[64];
  int t = threadIdx.x;
  int v = binh[t];
  s[t] = v;
  __syncthreads();
  for (int d = 1; d < 64; d <<= 1) {
    int x = (t >= d) ? s[t - d] : 0;
    __syncthreads();
    s[t] += x;
    __syncthreads();
  }
  binc[t] = s[t] - v;
}

// place nodes into degree-sorted positions (two-level reservation)
__global__ __launch_bounds__(256) void k_place(const int* __restrict__ deg,
                                               int* __restrict__ binc,
                                               int* __restrict__ nap,
                                               int* __restrict__ posv,
                                               int* __restrict__ pdgp) {
  __shared__ int h[64], rb[64], lc[64];
  const int t = threadIdx.x;
  if (t < 64) h[t] = 0;
  __syncthreads();
  int v = blockIdx.x * 256 + t;
  int pdeg = 0, bin = 0;
  bool valid = v < NN;
  if (valid) {
    pdeg = (deg[v] + 3) & ~3;
    bin = pdeg >> 2;
    if (bin > 63) bin = 63;
    atomicAdd(&h[bin], 1);
  }
  __syncthreads();
  if (t < 64) {
    rb[t] = h[t] ? atomicAdd(&binc[t], h[t]) : 0;
    lc[t] = 0;
  }
  __syncthreads();
  if (valid) {
    int slot = atomicAdd(&lc[bin], 1);
    int pos = rb[bin] + slot;
    nap[pos] = v;
    posv[v] = pos;
    pdgp[pos] = pdeg;
  }
}

// ---------------- exclusive scan over pdgp ----------------
__global__ __launch_bounds__(256) void k_scan1(const int* __restrict__ pdgp,
                                               int* __restrict__ rp,
                                               int* __restrict__ part) {
  __shared__ int s[256];
  int b = blockIdx.x, t = threadIdx.x;
  int base = b * 1024 + t * 4;
  int v0 = (base + 0 < NN) ? pdgp[base + 0] : 0;
  int v1 = (base + 1 < NN) ? pdgp[base + 1] : 0;
  int v2 = (base + 2 < NN) ? pdgp[base + 2] : 0;
  int v3 = (base + 3 < NN) ? pdgp[base + 3] : 0;
  int tot = v0 + v1 + v2 + v3;
  s[t] = tot;
  __syncthreads();
  for (int d = 1; d < 256; d <<= 1) {
    int x = (t >= d) ? s[t - d] : 0;
    __syncthreads();
    s[t] += x;
    __syncthreads();
  }
  int excl = s[t] - tot;
  if (t == 255) part[b] = s[255];
  if (base + 0 < NN) rp[base + 0] = excl;
  if (base + 1 < NN) rp[base + 1] = excl + v0;
  if (base + 2 < NN) rp[base + 2] = excl + v0 + v1;
  if (base + 3 < NN) rp[base + 3] = excl + v0 + v1 + v2;
}

__global__ __launch_bounds__(128) void k_scan2(const int* __restrict__ part,
                                               int* __restrict__ offs) {
  __shared__ int s[128];
  int t = threadIdx.x;
  int v = (t < 98) ? part[t] : 0;
  s[t] = v;
  __syncthreads();
  for (int d = 1; d < 128; d <<= 1) {
    int x = (t >= d) ? s[t - d] : 0;
    __syncthreads();
    s[t] += x;
    __syncthreads();
  }
  if (t < 98) offs[t] = s[t] - v;
}

__global__ __launch_bounds__(256) void k_scan3(int* __restrict__ rp,
                                               const int* __restrict__ offs,
                                               const int* __restrict__ part) {
  int b = blockIdx.x, t = threadIdx.x;
  int o = offs[b];
  int base = b * 1024 + t * 4;
#pragma unroll
  for (int j = 0; j < 4; ++j) {
    int i = base + j;
    if (i < NN) rp[i] += o;
  }
  if (b == 0 && t == 0) rp[NN] = offs[97] + part[97];
}

// cur (by node) + per-position dis^2 / sqrt(deg)
__global__ __launch_bounds__(256) void k_curinit(const int* __restrict__ nap,
                                                 const int* __restrict__ rp,
                                                 const int* __restrict__ deg,
                                                 const float* __restrict__ dis,
                                                 int* __restrict__ cur,
                                                 float* __restrict__ d2p,
                                                 float* __restrict__ dsqp) {
  int p = blockIdx.x * 256 + threadIdx.x;
  if (p < NN) {
    int v = nap[p];
    cur[v] = rp[p];
    float dv = dis[v];
    d2p[p] = dv * dv;
    int d = deg[v];
    dsqp[p] = d > 0 ? sqrtf((float)d) : 0.0f;
  }
}

// ---------------- phase B: fill CSR (position-translated src), XCD-matched --------
__global__ __launch_bounds__(256) void k_fill2(const int2* __restrict__ epk8,
                                               const int* __restrict__ bcnt,
                                               const int* __restrict__ posv,
                                               int* __restrict__ cur,
                                               int* __restrict__ csrc) {
  const int bucket = blockIdx.x & 7;
  const int chunk = blockIdx.x >> 3;
  const int cnt = bcnt[bucket];
  const int lo = chunk * EPB_B;
  int n = cnt - lo;
  if (n > EPB_B) n = EPB_B;
  const int2* src = epk8 + (size_t)bucket * BCAP + lo;
  for (int i = threadIdx.x; i < n; i += 256) {
    int2 rc = src[i];
    int p = atomicAdd(&cur[rc.y], 1);
    csrc[p] = posv[rc.x];
  }
}

// pad each position's slots up to rounded length with dummy pos = NN (zero row)
__global__ __launch_bounds__(256) void k_pad(const int* __restrict__ nap,
                                             const int* __restrict__ cur,
                                             const int* __restrict__ rp,
                                             int* __restrict__ csrc) {
  int p = blockIdx.x * 256 + threadIdx.x;
  if (p < NN) {
    int v = nap[p];
    int q = cur[v], e = rp[p + 1];
    for (; q < e; ++q) csrc[q] = NN;
  }
}

// ---------------- cvt-transpose (high bf16 only): dst[n][k] = bf16(src[k][n]) -----
__global__ __launch_bounds__(256) void k_cvtT(const float* __restrict__ src,
                                              unsigned short* __restrict__ dh,
                                              int K, int N) {
  int idx = blockIdx.x * 256 + threadIdx.x;
  if (idx >= K * N) return;
  int n = idx / K, k = idx - n * K;
  dh[idx] = bf16_rne(src[(size_t)k * N + n]);
}

// ---------------- fused MLP: u0[pos]=bf16(dis*h), out=g0*h (r12, unchanged) -------
__global__ __launch_bounds__(512, 2) void k_mlp(const float* __restrict__ X,
                                                const unsigned short* __restrict__ W1Th,
                                                const float* __restrict__ bias1,
                                                const unsigned short* __restrict__ W2Th,
                                                const float* __restrict__ bias2,
                                                const float* __restrict__ gamma,
                                                const float* __restrict__ dis,
                                                const int* __restrict__ posv,
                                                unsigned short* __restrict__ u0,
                                                float* __restrict__ out) {
  __shared__ __align__(16) unsigned short Ah[2][4096];   // 16 KB (reused: W2 stage)
  __shared__ __align__(16) unsigned short Bh[2][8192];   // 32 KB (reused: h1 halves)
  const int t = threadIdx.x;
  const int m0 = blockIdx.x * 128;
  const int w = t >> 6, lane = t & 63;
  const int wm = w >> 2, wn = w & 3;

  const int arow = t >> 2;
  const int achk = t & 3;
  int axrow = m0 + arow; if (axrow >= NN) axrow = NN - 1;
  const float* aptr = X + (size_t)axrow * INCH + achk * 8;
  int aidx = (arow >> 4) * 512 + ((arow & 15) + achk * 16) * 8;
  aidx ^= ((aidx >> 7) & 3) << 4;                      // XOR-swizzle (0 conflicts)
  const int aroff = (lane * 8) ^ (((lane >> 4) & 3) << 4);

  const int bn0 = (w * 16) + (lane & 15);
  const int bko = (lane >> 4) * 8;
  const unsigned short* bs0 = W1Th + (size_t)bn0 * INCH + bko;
  const unsigned short* bs1 = W1Th + (size_t)(bn0 + 128) * INCH + bko;

  f32x4 acc[4][4] = {};
  float4 av0, av1;

  av0 = *(const float4*)(aptr);
  av1 = *(const float4*)(aptr + 4);
  GLOAD_LDS16(bs0, &Bh[0][w * 512]);
  GLOAD_LDS16(bs1, &Bh[0][(w + 8) * 512]);
  {
    float af[8] = {av0.x, av0.y, av0.z, av0.w, av1.x, av1.y, av1.z, av1.w};
    short8 ah;
#pragma unroll
    for (int i = 0; i < 8; ++i) {
      unsigned int u = __float_as_uint(af[i]);
      ah[i] = (short)((u + 0x7fffu + ((u >> 16) & 1u)) >> 16);
    }
    *(short8*)&Ah[0][aidx] = ah;
  }
  __syncthreads();

#pragma unroll
  for (int it = 0; it < 16; ++it) {
    const int cur = it & 1, nxt = cur ^ 1;
    const int k0 = it * 32;
    if (it < 15) {
      av0 = *(const float4*)(aptr + k0 + 32);
      av1 = *(const float4*)(aptr + k0 + 36);
      GLOAD_LDS16(bs0 + k0 + 32, &Bh[nxt][w * 512]);
      GLOAD_LDS16(bs1 + k0 + 32, &Bh[nxt][(w + 8) * 512]);
    }
    short8 afrag[4];
#pragma unroll
    for (int mf = 0; mf < 4; ++mf)
      afrag[mf] = *(const short8*)&Ah[cur][(wm * 4 + mf) * 512 + aroff];
#pragma unroll
    for (int nf = 0; nf < 4; ++nf) {
      short8 bfh = *(const short8*)&Bh[cur][(wn * 4 + nf) * 512 + lane * 8];
#pragma unroll
      for (int mf = 0; mf < 4; ++mf) {
        acc[mf][nf] = __builtin_amdgcn_mfma_f32_16x16x32_bf16(afrag[mf], bfh, acc[mf][nf], 0, 0, 0);
      }
    }
    if (it < 15) {
      float af[8] = {av0.x, av0.y, av0.z, av0.w, av1.x, av1.y, av1.z, av1.w};
      short8 ah;
#pragma unroll
      for (int i = 0; i < 8; ++i) {
        unsigned int u = __float_as_uint(af[i]);
        ah[i] = (short)((u + 0x7fffu + ((u >> 16) & 1u)) >> 16);
      }
      *(short8*)&Ah[nxt][aidx] = ah;
    }
    __syncthreads();
  }

  // ================= fused GEMM2 =================
  unsigned short* AhF = &Ah[0][0];   // W2Th staged here (16 units)
  unsigned short* BhF = &Bh[0][0];   // h1 half (32 units of 512)

  {
#pragma unroll
    for (int q = 0; q < 2; ++q) {
      int u = w * 2 + q;
      int ngrp = u >> 3, k32 = u & 7;
      const unsigned short* src = W2Th + (size_t)(ngrp * 16 + (lane & 15)) * HIDCH
                                       + k32 * 32 + (lane >> 4) * 8;
      GLOAD_LDS16(src, &AhF[u * 512]);
    }
  }

  const int row15b = (lane >> 4) << 2;
  const int kcol = lane & 15;
  float bset[4];
#pragma unroll
  for (int nf = 0; nf < 4; ++nf) bset[nf] = bias1[wn * 64 + nf * 16 + kcol];

  if (wn < 2) {
    const int kbase = wn * 64;
#pragma unroll
    for (int nf = 0; nf < 4; ++nf) {
      int kh = kbase + nf * 16 + kcol;
      int base = ((wm * 4) * 4 + (kh >> 5)) * 512 + ((kh >> 3) & 3) * 128 + (kh & 7);
#pragma unroll
      for (int mf = 0; mf < 4; ++mf) {
#pragma unroll
        for (int r = 0; r < 4; ++r) {
          float h = fmaxf(acc[mf][nf][r] + bset[nf], 0.f);
          BhF[base + mf * 2048 + (row15b + r) * 8] = bf16_rne(h);
        }
      }
    }
  }
  __syncthreads();

  f32x4 acc2[2] = {};
#pragma unroll
  for (int s = 0; s < 4; ++s) {
    short8 a2 = *(const short8*)&BhF[(w * 4 + s) * 512 + lane * 8];
#pragma unroll
    for (int nf = 0; nf < 2; ++nf) {
      short8 bf = *(const short8*)&AhF[(nf * 8 + s) * 512 + lane * 8];
      acc2[nf] = __builtin_amdgcn_mfma_f32_16x16x32_bf16(a2, bf, acc2[nf], 0, 0, 0);
    }
  }
  __syncthreads();

  if (wn >= 2) {
    const int kbase = (wn - 2) * 64;
#pragma unroll
    for (int nf = 0; nf < 4; ++nf) {
      int kh = kbase + nf * 16 + kcol;
      int base = ((wm * 4) * 4 + (kh >> 5)) * 512 + ((kh >> 3) & 3) * 128 + (kh & 7);
#pragma unroll
      for (int mf = 0; mf < 4; ++mf) {
#pragma unroll
        for (int r = 0; r < 4; ++r) {
          float h = fmaxf(acc[mf][nf][r] + bset[nf], 0.f);
          BhF[base + mf * 2048 + (row15b + r) * 8] = bf16_rne(h);
        }
      }
    }
  }
  __syncthreads();

#pragma unroll
  for (int s = 0; s < 4; ++s) {
    short8 a2 = *(const short8*)&BhF[(w * 4 + s) * 512 + lane * 8];
#pragma unroll
    for (int nf = 0; nf < 2; ++nf) {
      short8 bf = *(const short8*)&AhF[(nf * 8 + 4 + s) * 512 + lane * 8];
      acc2[nf] = __builtin_amdgcn_mfma_f32_16x16x32_bf16(a2, bf, acc2[nf], 0, 0, 0);
    }
  }

  const float g0 = gamma[0];
  const float b2c[2] = {bias2[kcol], bias2[16 + kcol]};
#pragma unroll
  for (int nf = 0; nf < 2; ++nf) {
#pragma unroll
    for (int r = 0; r < 4; ++r) {
      int row = m0 + w * 16 + row15b + r;
      if (row < NN) {
        float h = acc2[nf][r] + b2c[nf];
        float dv = dis[row];
        size_t op = (size_t)posv[row] * 32 + nf * 16 + kcol;
        u0[op] = bf16_rne(dv * h);
        out[(size_t)row * 32 + nf * 16 + kcol] = g0 * h;
      }
    }
  }
}

// ---------------- hop gather core (16-edge unroll for MLP depth) -------------------
__device__ __forceinline__ void hop_sum(const unsigned int* __restrict__ Uin,
                                        const int* __restrict__ csrc,
                                        int s, int e, int li,
                                        float& Sx, float& Sy) {
  float ax0 = 0.f, ay0 = 0.f, ax1 = 0.f, ay1 = 0.f;
  float ax2 = 0.f, ay2 = 0.f, ax3 = 0.f, ay3 = 0.f;
  int j = s;
  for (; j + 16 <= e; j += 16) {
    int4 sa = *(const int4*)&csrc[j];
    int4 sb = *(const int4*)&csrc[j + 4];
    int4 sc = *(const int4*)&csrc[j + 8];
    int4 sd = *(const int4*)&csrc[j + 12];
    unsigned int w0 = Uin[(size_t)sa.x * 16 + li];
    unsigned int w1 = Uin[(size_t)sa.y * 16 + li];
    unsigned int w2 = Uin[(size_t)sa.z * 16 + li];
    unsigned int w3 = Uin[(size_t)sa.w * 16 + li];
    unsigned int w4 = Uin[(size_t)sb.x * 16 + li];
    unsigned int w5 = Uin[(size_t)sb.y * 16 + li];
    unsigned int w6 = Uin[(size_t)sb.z * 16 + li];
    unsigned int w7 = Uin[(size_t)sb.w * 16 + li];
    unsigned int w8 = Uin[(size_t)sc.x * 16 + li];
    unsigned int w9 = Uin[(size_t)sc.y * 16 + li];
    unsigned int wa = Uin[(size_t)sc.z * 16 + li];
    unsigned int wb = Uin[(size_t)sc.w * 16 + li];
    unsigned int wc = Uin[(size_t)sd.x * 16 + li];
    unsigned int wd = Uin[(size_t)sd.y * 16 + li];
    unsigned int we = Uin[(size_t)sd.z * 16 + li];
    unsigned int wf = Uin[(size_t)sd.w * 16 + li];
    ax0 += bflo(w0); ay0 += bfhi(w0);
    ax1 += bflo(w1); ay1 += bfhi(w1);
    ax2 += bflo(w2); ay2 += bfhi(w2);
    ax3 += bflo(w3); ay3 += bfhi(w3);
    ax0 += bflo(w4); ay0 += bfhi(w4);
    ax1 += bflo(w5); ay1 += bfhi(w5);
    ax2 += bflo(w6); ay2 += bfhi(w6);
    ax3 += bflo(w7); ay3 += bfhi(w7);
    ax0 += bflo(w8); ay0 += bfhi(w8);
    ax1 += bflo(w9); ay1 += bfhi(w9);
    ax2 += bflo(wa); ay2 += bfhi(wa);
    ax3 += bflo(wb); ay3 += bfhi(wb);
    ax0 += bflo(wc); ay0 += bfhi(wc);
    ax1 += bflo(wd); ay1 += bfhi(wd);
    ax2 += bflo(we); ay2 += bfhi(we);
    ax3 += bflo(wf); ay3 += bfhi(wf);
  }
  for (; j + 4 <= e; j += 4) {
    int4 sa = *(const int4*)&csrc[j];
    unsigned int w0 = Uin[(size_t)sa.x * 16 + li];
    unsigned int w1 = Uin[(size_t)sa.y * 16 + li];
    unsigned int w2 = Uin[(size_t)sa.z * 16 + li];
    unsigned int w3 = Uin[(size_t)sa.w * 16 + li];
    ax0 += bflo(w0); ay0 += bfhi(w0);
    ax1 += bflo(w1); ay1 += bfhi(w1);
    ax2 += bflo(w2); ay2 += bfhi(w2);
    ax3 += bflo(w3); ay3 += bfhi(w3);
  }
  Sx = (ax0 + ax1) + (ax2 + ax3);
  Sy = (ay0 + ay1) + (ay2 + ay3);
}

// ---------------- hop k (1..9): u_k[p] = d2p[p] * sum u_{k-1}[src] -----------------
__global__ __launch_bounds__(256) void k_hop(const unsigned short* __restrict__ Uin,
                                             unsigned short* __restrict__ Uout,
                                             const int* __restrict__ rp,
                                             const int* __restrict__ csrc,
                                             const float* __restrict__ d2p) {
  const int t = threadIdx.x;
  const int g = t >> 4;
  const int li = t & 15;
  const int p = blockIdx.x * 16 + g;
  const int s = rp[p], e = rp[p + 1];
  float Sx, Sy;
  hop_sum((const unsigned int*)Uin, csrc, s, e, li, Sx, Sy);
  const float d2 = d2p[p];
  unsigned int packed = (unsigned int)bf16_rne(d2 * Sx) |
                        ((unsigned int)bf16_rne(d2 * Sy) << 16);
  ((unsigned int*)Uout)[(size_t)p * 16 + li] = packed;
}

// ---------------- hop 10 + merge fused: out[v] += sum_k gamma_k*sqrt(deg)*u_k ------
__global__ __launch_bounds__(256) void k_hop_last(const unsigned short* __restrict__ u0,
                                                  const int* __restrict__ rp,
                                                  const int* __restrict__ csrc,
                                                  const float* __restrict__ d2p,
                                                  const int* __restrict__ nap,
                                                  const float* __restrict__ dsqp,
                                                  const float* __restrict__ gamma,
                                                  float* __restrict__ out) {
  const int t = threadIdx.x;
  const int g = t >> 4;
  const int li = t & 15;
  const int p = blockIdx.x * 16 + g;
  const int s = rp[p], e = rp[p + 1];
  const unsigned short* u9 = u0 + (size_t)(KHOPS - 1) * USH;
  float Sx, Sy;
  hop_sum((const unsigned int*)u9, csrc, s, e, li, Sx, Sy);
  const float d2 = d2p[p];
  const float u10x = d2 * Sx, u10y = d2 * Sy;

  const int v = nap[p];
  const float f = dsqp[p];
  const size_t o = (size_t)v * 32 + li * 2;
  float2 acc = *(const float2*)&out[o];
#pragma unroll
  for (int k = 1; k < KHOPS; ++k) {
    unsigned int w = ((const unsigned int*)(u0 + (size_t)k * USH))[(size_t)p * 16 + li];
    float gk = gamma[k] * f;
    acc.x = fmaf(gk, bflo(w), acc.x);
    acc.y = fmaf(gk, bfhi(w), acc.y);
  }
  const float g10 = gamma[KHOPS] * f;
  acc.x = fmaf(g10, u10x, acc.x);
  acc.y = fmaf(g10, u10y, acc.y);
  *(float2*)&out[o] = acc;
}

extern "C" void kernel_launch(void* const* d_in, const int* in_sizes, int n_in,
                              void* d_out, int out_size, void* d_ws, size_t ws_size,
                              hipStream_t stream) {
  const float* x     = (const float*)d_in[0];
  const int*   ei    = (const int*)d_in[1];
  const float* W1    = (const float*)d_in[2];
  const float* b1    = (const float*)d_in[3];
  const float* W2    = (const float*)d_in[4];
  const float* b2    = (const float*)d_in[5];
  const float* gamma = (const float*)d_in[6];
  float* out = (float*)d_out;

  char* ws = (char*)d_ws;
  unsigned short* u0   = (unsigned short*)(ws + OFF_U0);
  unsigned short* w1th = (unsigned short*)(ws + OFF_W1TH);
  unsigned short* w2th = (unsigned short*)(ws + OFF_W2TH);
  int*   deg  = (int*)(ws + OFF_DEG);
  float* dis  = (float*)(ws + OFF_DIS);
  int*   rp   = (int*)(ws + OFF_RP);
  int*   cur  = (int*)(ws + OFF_CUR);
  int*   nap  = (int*)(ws + OFF_NAP);
  int*   posv = (int*)(ws + OFF_POSV);
  int*   pdgp = (int*)(ws + OFF_PDGP);
  float* d2p  = (float*)(ws + OFF_D2P);
  float* dsqp = (float*)(ws + OFF_DSQP);
  int*   csrc = (int*)(ws + OFF_CSR);
  int*   part = (int*)(ws + OFF_PART);
  int*   offs = (int*)(ws + OFF_OFFS);
  int*   bcnt = (int*)(ws + OFF_BCNT);
  int*   binh = (int*)(ws + OFF_BINH);
  int*   binc = (int*)(ws + OFF_BINC);
  int2*  epk8 = (int2*)(ws + OFF_EPK8);

  // init counters (one kernel instead of 3 memsets)
  k_zero<<<(NN + 255) / 256, 256, 0, stream>>>(deg, bcnt, binh);

  // weight prep (tiny, high bf16 only)
  k_cvtT<<<(INCH * HIDCH + 255) / 256, 256, 0, stream>>>(W1, w1th, INCH, HIDCH);
  k_cvtT<<<(HIDCH * OUTCH + 255) / 256, 256, 0, stream>>>(W2, w2th, HIDCH, OUTCH);

  // graph prep: bucket (+deg), dis(+hist), degree-sort, scan, XCD-local fill, pad
  k_bucket<<<(NE + EPB_A - 1) / EPB_A, 256, 0, stream>>>(ei, deg, bcnt, epk8);
  k_dis<<<(NN + 255) / 256, 256, 0, stream>>>(deg, dis, u0, binh);
  k_binscan<<<1, 64, 0, stream>>>(binh, binc);
  k_place<<<(NN + 255) / 256, 256, 0, stream>>>(deg, binc, nap, posv, pdgp);
  k_scan1<<<98, 256, 0, stream>>>(pdgp, rp, part);
  k_scan2<<<1, 128, 0, stream>>>(part, offs);
  k_scan3<<<98, 256, 0, stream>>>(rp, offs, part);
  k_curinit<<<(NN + 255) / 256, 256, 0, stream>>>(nap, rp, deg, dis, cur, d2p, dsqp);
  k_fill2<<<(BCAP / EPB_B) * NBKT, 256, 0, stream>>>(epk8, bcnt, posv, cur, csrc);
  k_pad<<<(NN + 255) / 256, 256, 0, stream>>>(nap, cur, rp, csrc);

  // fused MLP (gemm1 + gemm2): writes u0[pos] and out = g0*h
  k_mlp<<<(NN + 127) / 128, 512, 0, stream>>>(x, w1th, b1, w2th, b2, gamma, dis,
                                              posv, u0, out);

  // propagation: hops 1..9 into tables, hop 10 fused with gamma merge
  for (int k = 1; k < KHOPS; ++k) {
    unsigned short* uin  = u0 + (size_t)(k - 1) * USH;
    unsigned short* uout = u0 + (size_t)k * USH;
    k_hop<<<NN / 16, 256, 0, stream>>>(uin, uout, rp, csrc, d2p);
  }
  k_hop_last<<<NN / 16, 256, 0, stream>>>(u0, rp, csrc, d2p, nap, dsqp, gamma, out);
}